// Round 8
// baseline (722.876 us; speedup 1.0000x reference)
//
#include <hip/hip_runtime.h>
#include <cmath>

#define T_SEQ 2048
#define C_DIM 1024
#define BM 128
#define BN 128
#define BK 32

typedef unsigned short u16;
typedef unsigned int u32;
typedef short bf16x8 __attribute__((ext_vector_type(8)));
typedef _Float16 f16x8 __attribute__((ext_vector_type(8)));
typedef float f32x4 __attribute__((ext_vector_type(4)));
typedef unsigned short u16x8 __attribute__((ext_vector_type(8)));

#define AS1 __attribute__((address_space(1)))
#define AS3 __attribute__((address_space(3)))

__device__ __forceinline__ u16 f2bf(float f) {
    u32 u = __builtin_bit_cast(u32, f);
    u32 r = u + 0x7fffu + ((u >> 16) & 1u);
    return (u16)(r >> 16);
}
__device__ __forceinline__ u16 f2h(float f) {
    return __builtin_bit_cast(u16, (_Float16)f);
}
__device__ __forceinline__ float h2f(u16 h) {
    return (float)__builtin_bit_cast(_Float16, h);
}
__device__ __forceinline__ void gl_lds16(const void* g, void* l) {
    __builtin_amdgcn_global_load_lds((const AS1 u32*)g, (AS3 u32*)l, 16, 0, 0);
}

// XCD-aware bijective block swizzle (T1): all our grids have nwg % 8 == 0.
__device__ __forceinline__ int xcd_swz(int lin, int nwg) {
    return (lin & 7) * (nwg >> 3) + (lin >> 3);
}

// ---------------------------------------------------------------------------
// MFMA GEMM: C[M,N] = A[M,K] @ B^T with B[N,K] row-major (K-contig).
// ASTAGE: 0 = A is 16-bit via global_load_lds
//         1 = A is f32, reg-staged with on-the-fly bf16 convert (DT must be 0)
// EPI:    0 = C f32 = acc    1 = C f32 *= acc    2 = C u16 = fp16(acc)
// DT:     0 = bf16   1 = fp16
// 128x128 tile, BK=32, 4 waves (2x2), dbuf LDS, XOR slot swizzle.
// ---------------------------------------------------------------------------
template<int ASTAGE, int EPI, int DT>
__global__ __launch_bounds__(256)
void mfma_gemm(const void* __restrict__ Abase, const u16* __restrict__ B0,
               void* __restrict__ Cout, int M, int N, int K)
{
    __shared__ u16 lds[2 * 2 * 4096];   // 2 buffers x (A, B) x 8KB
    const int tid  = threadIdx.x;
    const int lane = tid & 63;
    const int wid  = tid >> 6;
    const int wr = wid >> 1, wc = wid & 1;
    const int gx = gridDim.x;
    const int lin = xcd_swz(blockIdx.x + gx * blockIdx.y, gx * gridDim.y);
    const int m0 = (lin / gx) * BM;
    const int n0 = (lin % gx) * BN;
    const int NT = K / BK;

    f32x4 acc[4][4] = {};

    auto stage = [&](int it, int buf) {
        const int k0 = it * BK;
        u16* base = &lds[buf * 8192];
        #pragma unroll
        for (int i = 0; i < 2; ++i) {
            const int chunk = wid + 4 * i;
            const int rloc  = chunk * 16 + (lane >> 2);
            const int slot  = (lane & 3) ^ ((rloc >> 1) & 3);
            gl_lds16(B0 + (size_t)(n0 + rloc) * K + k0 + slot * 8,
                     base + 4096 + chunk * 512);
        }
        if constexpr (ASTAGE == 0) {
            const u16* Ap = (const u16*)Abase;
            #pragma unroll
            for (int i = 0; i < 2; ++i) {
                const int chunk = wid + 4 * i;
                const int rloc  = chunk * 16 + (lane >> 2);
                const int slot = (lane & 3) ^ ((rloc >> 1) & 3);
                gl_lds16(Ap + (size_t)(m0 + rloc) * K + k0 + slot * 8,
                         base + chunk * 512);
            }
        } else {
            const float* Af = (const float*)Abase;
            const int r = tid >> 1, h = tid & 1;
            const float* src = Af + (size_t)(m0 + r) * K + k0 + h * 16;
            const float4 q0 = ((const float4*)src)[0];
            const float4 q1 = ((const float4*)src)[1];
            const float4 q2 = ((const float4*)src)[2];
            const float4 q3 = ((const float4*)src)[3];
            float v[16] = {q0.x,q0.y,q0.z,q0.w, q1.x,q1.y,q1.z,q1.w,
                           q2.x,q2.y,q2.z,q2.w, q3.x,q3.y,q3.z,q3.w};
            const int rb = r * 32;
            #pragma unroll
            for (int s2 = 0; s2 < 2; ++s2) {
                const int slot = 2 * h + s2;
                const int sp = slot ^ ((r >> 1) & 3);
                u16x8 w;
                #pragma unroll
                for (int j = 0; j < 8; ++j) w[j] = f2bf(v[s2 * 8 + j]);
                *(u16x8*)&base[rb + sp * 8] = w;
            }
        }
    };

    auto compute = [&](int buf) {
        const u16* base = &lds[buf * 8192];
        if constexpr (DT == 0) {
            bf16x8 a[4], b[4];
            #pragma unroll
            for (int f = 0; f < 4; ++f) {
                const int row = wr * 64 + f * 16 + (lane & 15);
                const int sp  = ((lane >> 4) & 3) ^ ((row >> 1) & 3);
                a[f] = *(const bf16x8*)&base[row * 32 + sp * 8];
                const int rowb = wc * 64 + f * 16 + (lane & 15);
                const int spb  = ((lane >> 4) & 3) ^ ((rowb >> 1) & 3);
                b[f] = *(const bf16x8*)&base[4096 + rowb * 32 + spb * 8];
            }
            #pragma unroll
            for (int fm = 0; fm < 4; ++fm)
                #pragma unroll
                for (int fn = 0; fn < 4; ++fn)
                    acc[fm][fn] = __builtin_amdgcn_mfma_f32_16x16x32_bf16(a[fm], b[fn], acc[fm][fn], 0, 0, 0);
        } else {
            f16x8 a[4], b[4];
            #pragma unroll
            for (int f = 0; f < 4; ++f) {
                const int row = wr * 64 + f * 16 + (lane & 15);
                const int sp  = ((lane >> 4) & 3) ^ ((row >> 1) & 3);
                a[f] = *(const f16x8*)&base[row * 32 + sp * 8];
                const int rowb = wc * 64 + f * 16 + (lane & 15);
                const int spb  = ((lane >> 4) & 3) ^ ((rowb >> 1) & 3);
                b[f] = *(const f16x8*)&base[4096 + rowb * 32 + spb * 8];
            }
            #pragma unroll
            for (int fm = 0; fm < 4; ++fm)
                #pragma unroll
                for (int fn = 0; fn < 4; ++fn)
                    acc[fm][fn] = __builtin_amdgcn_mfma_f32_16x16x32_f16(a[fm], b[fn], acc[fm][fn], 0, 0, 0);
        }
    };

    stage(0, 0);
    int cur = 0;
    for (int it = 0; it < NT; ++it) {
        __syncthreads();
        if (it + 1 < NT) stage(it + 1, cur ^ 1);
        compute(cur);
        cur ^= 1;
    }

    const int crow0 = m0 + wr * 64 + ((lane >> 4) << 2);
    const int ccol  = n0 + wc * 64 + (lane & 15);
    #pragma unroll
    for (int fm = 0; fm < 4; ++fm)
        #pragma unroll
        for (int fn = 0; fn < 4; ++fn)
            #pragma unroll
            for (int r = 0; r < 4; ++r) {
                const size_t idx = (size_t)(crow0 + fm * 16 + r) * N + ccol + fn * 16;
                if constexpr (EPI == 0)      ((float*)Cout)[idx] = acc[fm][fn][r];
                else if constexpr (EPI == 1) ((float*)Cout)[idx] *= acc[fm][fn][r];
                else                         ((u16*)Cout)[idx] = f2h(acc[fm][fn][r]);
            }
}

// ---------------------------------------------------------------------------
// Fused causal-conv + gate:  H = bf16( tanh(conv(y,Wf)) * sigmoid(conv(y,Wg)) )
// A = yb bf16 [M,1024]; Wfgt layout [tap][F/G][n][k] bf16.
// Per block: 128x128 tile of BOTH F and G (accF+accG, 32 MFMA/K-step).
// Pass 0 = tap 0 (A shifted by one row, zero at t==0); pass 1 = tap 1.
// ---------------------------------------------------------------------------
__global__ __launch_bounds__(256)
void conv_gate(const u16* __restrict__ A, const u16* __restrict__ Wfgt,
               u16* __restrict__ H, int M)
{
    constexpr int KIT = C_DIM / BK;   // 32
    constexpr int NT  = 2 * KIT;      // 64
    __shared__ u16 lds[2 * 3 * 4096]; // 2 buf x (A, BF, BG)
    const int tid  = threadIdx.x;
    const int lane = tid & 63;
    const int wid  = tid >> 6;
    const int wr = wid >> 1, wc = wid & 1;
    const int gx = gridDim.x;
    const int lin = xcd_swz(blockIdx.x + gx * blockIdx.y, gx * gridDim.y);
    const int m0 = (lin / gx) * BM;
    const int n0 = (lin % gx) * BN;

    f32x4 accF[4][4] = {};
    f32x4 accG[4][4] = {};

    auto stage = [&](int it, int buf) {
        const int p  = it / KIT;                 // tap
        const int k0 = (it - p * KIT) * BK;
        u16* base = &lds[buf * 12288];
        const u16* BF = Wfgt + (size_t)p * 2 * C_DIM * C_DIM;
        const u16* BG = BF + (size_t)C_DIM * C_DIM;
        const int sh = (p == 0) ? 1 : 0;
        #pragma unroll
        for (int i = 0; i < 2; ++i) {
            const int chunk = wid + 4 * i;
            const int rloc  = chunk * 16 + (lane >> 2);
            const int slot  = (lane & 3) ^ ((rloc >> 1) & 3);
            int grow = m0 + rloc - sh;
            if (grow < 0) grow = 0;
            gl_lds16(A + (size_t)grow * C_DIM + k0 + slot * 8,
                     base + chunk * 512);
            gl_lds16(BF + (size_t)(n0 + rloc) * C_DIM + k0 + slot * 8,
                     base + 4096 + chunk * 512);
            gl_lds16(BG + (size_t)(n0 + rloc) * C_DIM + k0 + slot * 8,
                     base + 8192 + chunk * 512);
        }
    };

    auto compute = [&](int buf) {
        const u16* base = &lds[buf * 12288];
        bf16x8 a[4], bf[4], bg[4];
        #pragma unroll
        for (int f = 0; f < 4; ++f) {
            const int row = wr * 64 + f * 16 + (lane & 15);
            const int sp  = ((lane >> 4) & 3) ^ ((row >> 1) & 3);
            a[f] = *(const bf16x8*)&base[row * 32 + sp * 8];
            const int rowb = wc * 64 + f * 16 + (lane & 15);
            const int spb  = ((lane >> 4) & 3) ^ ((rowb >> 1) & 3);
            bf[f] = *(const bf16x8*)&base[4096 + rowb * 32 + spb * 8];
            bg[f] = *(const bf16x8*)&base[8192 + rowb * 32 + spb * 8];
        }
        #pragma unroll
        for (int fm = 0; fm < 4; ++fm)
            #pragma unroll
            for (int fn = 0; fn < 4; ++fn) {
                accF[fm][fn] = __builtin_amdgcn_mfma_f32_16x16x32_bf16(a[fm], bf[fn], accF[fm][fn], 0, 0, 0);
                accG[fm][fn] = __builtin_amdgcn_mfma_f32_16x16x32_bf16(a[fm], bg[fn], accG[fm][fn], 0, 0, 0);
            }
    };

    stage(0, 0);
    int cur = 0;
    for (int it = 0; it < NT; ++it) {
        __syncthreads();
        // zero the t==0 row of the A tile for the shifted tap
        if ((it / KIT) == 0 && (m0 % T_SEQ) == 0) {
            if (tid < 4) {
                u16x8 z = {0,0,0,0,0,0,0,0};
                *(u16x8*)&lds[cur * 12288 + tid * 8] = z;
            }
            __syncthreads();
        }
        if (it + 1 < NT) stage(it + 1, cur ^ 1);
        compute(cur);
        cur ^= 1;
    }

    const int crow0 = m0 + wr * 64 + ((lane >> 4) << 2);
    const int ccol  = n0 + wc * 64 + (lane & 15);
    #pragma unroll
    for (int fm = 0; fm < 4; ++fm)
        #pragma unroll
        for (int fn = 0; fn < 4; ++fn)
            #pragma unroll
            for (int r = 0; r < 4; ++r) {
                const float fv = accF[fm][fn][r];
                const float gv = accG[fm][fn][r];
                const float th = 1.0f - 2.0f / (expf(2.0f * fv) + 1.0f);
                const float sg = 1.0f / (1.0f + expf(-gv));
                H[(size_t)(crow0 + fm * 16 + r) * C_DIM + ccol + fn * 16] = f2bf(th * sg);
            }
}

// ---------------------------------------------------------------------------
// Segmented parallel scan, register-resident, 128B-coalesced:
//   32 channels x 32 segments per block (1024 thr), 256 blocks.
//   reads kh (fp16 pairs, 128B/wave-group), writes kv bf16 IN-PLACE;
//   reads xh fp16 from the yb buffer, writes yb = bf16(x*scale) in place.
// ---------------------------------------------------------------------------
#define SSEG 32
#define SCHB 32
#define SSL (T_SEQ / SSEG)   // 64

__global__ __launch_bounds__(1024, 1)
void scan_kernel(u16* __restrict__ kq, u16* __restrict__ xyb)
{
    __shared__ float  lmax[SSEG][SCHB];
    __shared__ float2 lprod[SSEG][SCHB];
    const int blk = blockIdx.x;
    const int b   = blk >> 5;                    // / 32 channel-groups
    const int c0  = (blk & 31) * SCHB;
    const int ch  = threadIdx.x & (SCHB - 1);    // 0..31
    const int seg = threadIdx.x >> 5;            // 0..31
    const int c   = c0 + ch;
    const int t0  = seg * SSL;
    const size_t baseh = (size_t)b * T_SEQ * 2048 + 2 * c + (size_t)t0 * 2048;
    const size_t base1 = (size_t)b * T_SEQ * C_DIM + c + (size_t)t0 * C_DIM;

    float vr[SSL], vi[SSL];

    // P1: load fp16 segment into registers; segment max
    float m = 0.f;
    {
        size_t idx = baseh;
        #pragma unroll
        for (int t = 0; t < SSL; ++t) {
            const u32 v = *(const u32*)&kq[idx];
            const float re = h2f((u16)(v & 0xffffu));
            const float im = h2f((u16)(v >> 16));
            vr[t] = re; vi[t] = im;
            m = fmaxf(m, sqrtf(re * re + im * im));
            idx += 2048;
        }
    }
    lmax[seg][ch] = m;
    __syncthreads();
    #pragma unroll
    for (int s = 1; s < SSEG; s <<= 1) {
        const float v = lmax[seg][ch];
        const float u = (seg >= s) ? lmax[seg - s][ch] : 0.f;
        __syncthreads();
        lmax[seg][ch] = fmaxf(v, u);
        __syncthreads();
    }
    const float premax = (seg > 0) ? lmax[seg - 1][ch] : 0.f;

    // P2: seeded running max; normalized running product in registers;
    //     yb = bf16(x * scale), x read as fp16 from the same buffer (in-place)
    float pr = 1.f, pi = 0.f;
    m = premax;
    {
        size_t idx1 = base1;
        #pragma unroll
        for (int t = 0; t < SSL; ++t) {
            const float a = sqrtf(vr[t] * vr[t] + vi[t] * vi[t]);
            m = fmaxf(m, a);
            const float inv = 1.f / m;
            const float r0 = vr[t] * inv, r1 = vi[t] * inv;
            const float nr = pr * r0 - pi * r1;
            const float ni = pr * r1 + pi * r0;
            pr = nr; pi = ni;
            vr[t] = nr; vi[t] = ni;
            const float xv = h2f(xyb[idx1]);
            xyb[idx1] = f2bf(xv * m);
            idx1 += C_DIM;
        }
    }
    lprod[seg][ch] = make_float2(pr, pi);
    __syncthreads();
    #pragma unroll
    for (int s = 1; s < SSEG; s <<= 1) {
        const float2 v = lprod[seg][ch];
        const float2 u = (seg >= s) ? lprod[seg - s][ch] : make_float2(1.f, 0.f);
        __syncthreads();
        lprod[seg][ch] = make_float2(u.x * v.x - u.y * v.y,
                                     u.x * v.y + u.y * v.x);
        __syncthreads();
    }
    float ppr = 1.f, ppi = 0.f;
    if (seg > 0) { const float2 pp = lprod[seg - 1][ch]; ppr = pp.x; ppi = pp.y; }

    // P3: scale by prefix product, write kv as bf16 pair (in-place)
    {
        size_t idx = baseh;
        #pragma unroll
        for (int t = 0; t < SSL; ++t) {
            const float nr = ppr * vr[t] - ppi * vi[t];
            const float ni = ppr * vi[t] + ppi * vr[t];
            *(u32*)&kq[idx] = ((u32)f2bf(ni) << 16) | (u32)f2bf(nr);
            idx += 2048;
        }
    }
}

// ---------------------------------------------------------------------------
// Prep kernels
// ---------------------------------------------------------------------------
__global__ void cvt_bf16(const float* __restrict__ src, u16* __restrict__ dst, int n)
{
    const int i = (blockIdx.x * blockDim.x + threadIdx.x) * 4;
    if (i >= n) return;
    const float4 v = *(const float4*)&src[i];
    ushort4 o;
    o.x = f2bf(v.x); o.y = f2bf(v.y); o.z = f2bf(v.z); o.w = f2bf(v.w);
    *(ushort4*)&dst[i] = o;
}

__global__ void cvt_f16(const float* __restrict__ src, u16* __restrict__ dst, int n)
{
    const int i = (blockIdx.x * blockDim.x + threadIdx.x) * 4;
    if (i >= n) return;
    const float4 v = *(const float4*)&src[i];
    ushort4 o;
    o.x = f2h(v.x); o.y = f2h(v.y); o.z = f2h(v.z); o.w = f2h(v.w);
    *(ushort4*)&dst[i] = o;
}

// Wf/Wg [2,K,N] (tap,k,n) -> Wfgt [tap][F/G][n][k] bf16
__global__ __launch_bounds__(256)
void wtrans(const float* __restrict__ Wf, const float* __restrict__ Wg,
            u16* __restrict__ dst)
{
    __shared__ float tile[64][65];
    const int z = blockIdx.z;
    const float* src = ((z < 2) ? Wf : Wg) + (size_t)(z & 1) * C_DIM * C_DIM;
    u16* d = dst + (size_t)(z & 1) * (2 * C_DIM) * C_DIM
                 + ((z < 2) ? (size_t)0 : (size_t)C_DIM * C_DIM);
    const int k0 = blockIdx.x * 64;
    const int n0 = blockIdx.y * 64;
    const int tx = threadIdx.x & 63, ty = threadIdx.x >> 6;
    #pragma unroll
    for (int i = 0; i < 16; ++i) {
        const int r = ty + i * 4;
        tile[r][tx] = src[(size_t)(k0 + r) * C_DIM + n0 + tx];
    }
    __syncthreads();
    #pragma unroll
    for (int i = 0; i < 16; ++i) {
        const int r = ty + i * 4;
        d[(size_t)(n0 + r) * C_DIM + k0 + tx] = f2bf(tile[tx][r]);
    }
}

// ---------------------------------------------------------------------------
// ws layout (bytes):
//   0         : kq  u16 [16384,2048]  67.1MB  (kh fp16 -> kv bf16 in-place)
//   67108864  : yb  u16 [16384,1024]  33.6MB  (xh fp16 -> yb bf16 in-place)
//   100663296 : hb  u16 [16384,1024]  33.6MB
//   134217728 : Wkh(f16) 4.2 | Wab 4.2 | Wfgt 8.4 | Wob 2.1   (~153MB total)
// ---------------------------------------------------------------------------
extern "C" void kernel_launch(void* const* d_in, const int* in_sizes, int n_in,
                              void* d_out, int out_size, void* d_ws, size_t ws_size,
                              hipStream_t stream)
{
    const float* x  = (const float*)d_in[0];
    const float* Wk = (const float*)d_in[1];
    const float* Wa = (const float*)d_in[2];
    const float* Wf = (const float*)d_in[3];
    const float* Wg = (const float*)d_in[4];
    const float* Wo = (const float*)d_in[5];
    float* out = (float*)d_out;

    const int M = 8 * T_SEQ;
    u16* kq   = (u16*)d_ws;
    u16* yb   = (u16*)((char*)d_ws + 67108864ull);   // xh first, then yb
    u16* hb   = (u16*)((char*)d_ws + 100663296ull);
    u16* Wkh  = (u16*)((char*)d_ws + 134217728ull);
    u16* Wab  = Wkh + 2048 * 1024;
    u16* Wfgt = Wab + 2048 * 1024;
    u16* Wob  = Wfgt + 2ull * 2048 * 1024;

    cvt_f16 <<<(2048 * 1024 / 4 + 255) / 256, 256, 0, stream>>>(Wk, Wkh, 2048 * 1024);
    cvt_bf16<<<(2048 * 1024 / 4 + 255) / 256, 256, 0, stream>>>(Wa, Wab, 2048 * 1024);
    cvt_bf16<<<(1024 * 1024 / 4 + 255) / 256, 256, 0, stream>>>(Wo, Wob, 1024 * 1024);
    wtrans  <<<dim3(16, 16, 4), 256, 0, stream>>>(Wf, Wg, Wfgt);
    cvt_f16 <<<(M * 1024 / 4) / 256, 256, 0, stream>>>(x, yb, M * 1024);  // xh

    // 1) kq = fp16( x @ Wk^T )  (fp16 MFMA, fp16 output)
    mfma_gemm<0, 2, 1><<<dim3(2048 / BN, M / BM), 256, 0, stream>>>(
        yb, Wkh, kq, M, 2048, 1024);

    // 2) scan: kv = bf16 cumprod (in-place over kq), yb = bf16(x*scale) in-place
    scan_kernel<<<256, 1024, 0, stream>>>(kq, yb);

    // 3) out = kv @ Wa^T  (bf16 A via global_load_lds)
    mfma_gemm<0, 0, 0><<<dim3(1024 / BN, M / BM), 256, 0, stream>>>(
        kq, Wab, out, M, 1024, 2048);

    // 4) hb = bf16(tanh(conv(yb,Wf)) * sigmoid(conv(yb,Wg)))
    conv_gate<<<dim3(1024 / BN, M / BM), 256, 0, stream>>>(yb, Wfgt, hb, M);

    // 5) out *= hb @ Wo^T
    mfma_gemm<0, 1, 0><<<dim3(1024 / BN, M / BM), 256, 0, stream>>>(
        hb, Wob, out, M, 1024, 1024);
}

// Round 9
// 506.063 us; speedup vs baseline: 1.4284x; 1.4284x over previous
//
#include <hip/hip_runtime.h>
#include <cmath>

#define T_SEQ 2048
#define C_DIM 1024
#define BM 128
#define BN 128
#define BK 32

typedef unsigned short u16;
typedef unsigned int u32;
typedef short bf16x8 __attribute__((ext_vector_type(8)));
typedef _Float16 f16x8 __attribute__((ext_vector_type(8)));
typedef float f32x4 __attribute__((ext_vector_type(4)));
typedef unsigned short u16x8 __attribute__((ext_vector_type(8)));

#define AS1 __attribute__((address_space(1)))
#define AS3 __attribute__((address_space(3)))

__device__ __forceinline__ u16 f2bf(float f) {
    u32 u = __builtin_bit_cast(u32, f);
    u32 r = u + 0x7fffu + ((u >> 16) & 1u);
    return (u16)(r >> 16);
}
__device__ __forceinline__ u16 f2h(float f) {
    return __builtin_bit_cast(u16, (_Float16)f);
}
__device__ __forceinline__ float h2f(u16 h) {
    return (float)__builtin_bit_cast(_Float16, h);
}
__device__ __forceinline__ void gl_lds16(const void* g, void* l) {
    __builtin_amdgcn_global_load_lds((const AS1 u32*)g, (AS3 u32*)l, 16, 0, 0);
}

// XCD-aware bijective block swizzle (T1): all our grids have nwg % 8 == 0.
__device__ __forceinline__ int xcd_swz(int lin, int nwg) {
    return (lin & 7) * (nwg >> 3) + (lin >> 3);
}

// ---------------------------------------------------------------------------
// MFMA GEMM: C[M,N] = A[M,K] @ B^T with B[N,K] row-major (K-contig).
// ASTAGE: 0 = A is 16-bit via global_load_lds
//         1 = A is f32, reg-staged with on-the-fly bf16 convert (DT must be 0)
// EPI:    0 = C f32 = acc    1 = C f32 *= acc    2 = C u16 = fp16(acc)
// DT:     0 = bf16   1 = fp16
// 128x128 tile, BK=32, 4 waves (2x2), dbuf LDS, XOR slot swizzle.
// ---------------------------------------------------------------------------
template<int ASTAGE, int EPI, int DT>
__global__ __launch_bounds__(256)
void mfma_gemm(const void* __restrict__ Abase, const u16* __restrict__ B0,
               void* __restrict__ Cout, int M, int N, int K)
{
    __shared__ u16 lds[2 * 2 * 4096];   // 2 buffers x (A, B) x 8KB
    const int tid  = threadIdx.x;
    const int lane = tid & 63;
    const int wid  = tid >> 6;
    const int wr = wid >> 1, wc = wid & 1;
    const int gx = gridDim.x;
    const int lin = xcd_swz(blockIdx.x + gx * blockIdx.y, gx * gridDim.y);
    const int m0 = (lin / gx) * BM;
    const int n0 = (lin % gx) * BN;
    const int NT = K / BK;

    f32x4 acc[4][4] = {};

    auto stage = [&](int it, int buf) {
        const int k0 = it * BK;
        u16* base = &lds[buf * 8192];
        #pragma unroll
        for (int i = 0; i < 2; ++i) {
            const int chunk = wid + 4 * i;
            const int rloc  = chunk * 16 + (lane >> 2);
            const int slot  = (lane & 3) ^ ((rloc >> 1) & 3);
            gl_lds16(B0 + (size_t)(n0 + rloc) * K + k0 + slot * 8,
                     base + 4096 + chunk * 512);
        }
        if constexpr (ASTAGE == 0) {
            const u16* Ap = (const u16*)Abase;
            #pragma unroll
            for (int i = 0; i < 2; ++i) {
                const int chunk = wid + 4 * i;
                const int rloc  = chunk * 16 + (lane >> 2);
                const int slot = (lane & 3) ^ ((rloc >> 1) & 3);
                gl_lds16(Ap + (size_t)(m0 + rloc) * K + k0 + slot * 8,
                         base + chunk * 512);
            }
        } else {
            const float* Af = (const float*)Abase;
            const int r = tid >> 1, h = tid & 1;
            const float* src = Af + (size_t)(m0 + r) * K + k0 + h * 16;
            const float4 q0 = ((const float4*)src)[0];
            const float4 q1 = ((const float4*)src)[1];
            const float4 q2 = ((const float4*)src)[2];
            const float4 q3 = ((const float4*)src)[3];
            float v[16] = {q0.x,q0.y,q0.z,q0.w, q1.x,q1.y,q1.z,q1.w,
                           q2.x,q2.y,q2.z,q2.w, q3.x,q3.y,q3.z,q3.w};
            const int rb = r * 32;
            #pragma unroll
            for (int s2 = 0; s2 < 2; ++s2) {
                const int slot = 2 * h + s2;
                const int sp = slot ^ ((r >> 1) & 3);
                u16x8 w;
                #pragma unroll
                for (int j = 0; j < 8; ++j) w[j] = f2bf(v[s2 * 8 + j]);
                *(u16x8*)&base[rb + sp * 8] = w;
            }
        }
    };

    auto compute = [&](int buf) {
        const u16* base = &lds[buf * 8192];
        if constexpr (DT == 0) {
            bf16x8 a[4], b[4];
            #pragma unroll
            for (int f = 0; f < 4; ++f) {
                const int row = wr * 64 + f * 16 + (lane & 15);
                const int sp  = ((lane >> 4) & 3) ^ ((row >> 1) & 3);
                a[f] = *(const bf16x8*)&base[row * 32 + sp * 8];
                const int rowb = wc * 64 + f * 16 + (lane & 15);
                const int spb  = ((lane >> 4) & 3) ^ ((rowb >> 1) & 3);
                b[f] = *(const bf16x8*)&base[4096 + rowb * 32 + spb * 8];
            }
            #pragma unroll
            for (int fm = 0; fm < 4; ++fm)
                #pragma unroll
                for (int fn = 0; fn < 4; ++fn)
                    acc[fm][fn] = __builtin_amdgcn_mfma_f32_16x16x32_bf16(a[fm], b[fn], acc[fm][fn], 0, 0, 0);
        } else {
            f16x8 a[4], b[4];
            #pragma unroll
            for (int f = 0; f < 4; ++f) {
                const int row = wr * 64 + f * 16 + (lane & 15);
                const int sp  = ((lane >> 4) & 3) ^ ((row >> 1) & 3);
                a[f] = *(const f16x8*)&base[row * 32 + sp * 8];
                const int rowb = wc * 64 + f * 16 + (lane & 15);
                const int spb  = ((lane >> 4) & 3) ^ ((rowb >> 1) & 3);
                b[f] = *(const f16x8*)&base[4096 + rowb * 32 + spb * 8];
            }
            #pragma unroll
            for (int fm = 0; fm < 4; ++fm)
                #pragma unroll
                for (int fn = 0; fn < 4; ++fn)
                    acc[fm][fn] = __builtin_amdgcn_mfma_f32_16x16x32_f16(a[fm], b[fn], acc[fm][fn], 0, 0, 0);
        }
    };

    stage(0, 0);
    int cur = 0;
    for (int it = 0; it < NT; ++it) {
        __syncthreads();
        if (it + 1 < NT) stage(it + 1, cur ^ 1);
        compute(cur);
        cur ^= 1;
    }

    const int crow0 = m0 + wr * 64 + ((lane >> 4) << 2);
    const int ccol  = n0 + wc * 64 + (lane & 15);
    #pragma unroll
    for (int fm = 0; fm < 4; ++fm)
        #pragma unroll
        for (int fn = 0; fn < 4; ++fn)
            #pragma unroll
            for (int r = 0; r < 4; ++r) {
                const size_t idx = (size_t)(crow0 + fm * 16 + r) * N + ccol + fn * 16;
                if constexpr (EPI == 0)      ((float*)Cout)[idx] = acc[fm][fn][r];
                else if constexpr (EPI == 1) ((float*)Cout)[idx] *= acc[fm][fn][r];
                else                         ((u16*)Cout)[idx] = f2h(acc[fm][fn][r]);
            }
}

// ---------------------------------------------------------------------------
// Fused causal-conv + gate:  H = bf16( tanh(conv(y,Wf)) * sigmoid(conv(y,Wg)) )
// A = yb bf16 [M,1024]; Wfgt layout [tap][F/G][n][k] bf16.
// Per block: 128x128 tile of BOTH F and G (accF+accG, 32 MFMA/K-step).
// Pass 0 = tap 0 (A shifted by one row, zero at t==0); pass 1 = tap 1.
// ---------------------------------------------------------------------------
__global__ __launch_bounds__(256)
void conv_gate(const u16* __restrict__ A, const u16* __restrict__ Wfgt,
               u16* __restrict__ H, int M)
{
    constexpr int KIT = C_DIM / BK;   // 32
    constexpr int NT  = 2 * KIT;      // 64
    __shared__ u16 lds[2 * 3 * 4096]; // 2 buf x (A, BF, BG)
    const int tid  = threadIdx.x;
    const int lane = tid & 63;
    const int wid  = tid >> 6;
    const int wr = wid >> 1, wc = wid & 1;
    const int gx = gridDim.x;
    const int lin = xcd_swz(blockIdx.x + gx * blockIdx.y, gx * gridDim.y);
    const int m0 = (lin / gx) * BM;
    const int n0 = (lin % gx) * BN;

    f32x4 accF[4][4] = {};
    f32x4 accG[4][4] = {};

    auto stage = [&](int it, int buf) {
        const int p  = it / KIT;                 // tap
        const int k0 = (it - p * KIT) * BK;
        u16* base = &lds[buf * 12288];
        const u16* BF = Wfgt + (size_t)p * 2 * C_DIM * C_DIM;
        const u16* BG = BF + (size_t)C_DIM * C_DIM;
        const int sh = (p == 0) ? 1 : 0;
        #pragma unroll
        for (int i = 0; i < 2; ++i) {
            const int chunk = wid + 4 * i;
            const int rloc  = chunk * 16 + (lane >> 2);
            const int slot  = (lane & 3) ^ ((rloc >> 1) & 3);
            int grow = m0 + rloc - sh;
            if (grow < 0) grow = 0;
            gl_lds16(A + (size_t)grow * C_DIM + k0 + slot * 8,
                     base + chunk * 512);
            gl_lds16(BF + (size_t)(n0 + rloc) * C_DIM + k0 + slot * 8,
                     base + 4096 + chunk * 512);
            gl_lds16(BG + (size_t)(n0 + rloc) * C_DIM + k0 + slot * 8,
                     base + 8192 + chunk * 512);
        }
    };

    auto compute = [&](int buf) {
        const u16* base = &lds[buf * 12288];
        bf16x8 a[4], bf[4], bg[4];
        #pragma unroll
        for (int f = 0; f < 4; ++f) {
            const int row = wr * 64 + f * 16 + (lane & 15);
            const int sp  = ((lane >> 4) & 3) ^ ((row >> 1) & 3);
            a[f] = *(const bf16x8*)&base[row * 32 + sp * 8];
            const int rowb = wc * 64 + f * 16 + (lane & 15);
            const int spb  = ((lane >> 4) & 3) ^ ((rowb >> 1) & 3);
            bf[f] = *(const bf16x8*)&base[4096 + rowb * 32 + spb * 8];
            bg[f] = *(const bf16x8*)&base[8192 + rowb * 32 + spb * 8];
        }
        #pragma unroll
        for (int fm = 0; fm < 4; ++fm)
            #pragma unroll
            for (int fn = 0; fn < 4; ++fn) {
                accF[fm][fn] = __builtin_amdgcn_mfma_f32_16x16x32_bf16(a[fm], bf[fn], accF[fm][fn], 0, 0, 0);
                accG[fm][fn] = __builtin_amdgcn_mfma_f32_16x16x32_bf16(a[fm], bg[fn], accG[fm][fn], 0, 0, 0);
            }
    };

    stage(0, 0);
    int cur = 0;
    for (int it = 0; it < NT; ++it) {
        __syncthreads();
        // zero the t==0 row of the A tile for the shifted tap
        if ((it / KIT) == 0 && (m0 % T_SEQ) == 0) {
            if (tid < 4) {
                u16x8 z = {0,0,0,0,0,0,0,0};
                *(u16x8*)&lds[cur * 12288 + tid * 8] = z;
            }
            __syncthreads();
        }
        if (it + 1 < NT) stage(it + 1, cur ^ 1);
        compute(cur);
        cur ^= 1;
    }

    const int crow0 = m0 + wr * 64 + ((lane >> 4) << 2);
    const int ccol  = n0 + wc * 64 + (lane & 15);
    #pragma unroll
    for (int fm = 0; fm < 4; ++fm)
        #pragma unroll
        for (int fn = 0; fn < 4; ++fn)
            #pragma unroll
            for (int r = 0; r < 4; ++r) {
                const float fv = accF[fm][fn][r];
                const float gv = accG[fm][fn][r];
                const float th = 1.0f - 2.0f / (expf(2.0f * fv) + 1.0f);
                const float sg = 1.0f / (1.0f + expf(-gv));
                H[(size_t)(crow0 + fm * 16 + r) * C_DIM + ccol + fn * 16] = f2bf(th * sg);
            }
}

// ---------------------------------------------------------------------------
// Segmented parallel scan, 3-pass STREAMING (no register arrays -> no spill),
// 128B-coalesced kq access (32 channels x 4B per 32-lane group):
//   P1: stream kq, segment max (of squared mag) -> LDS max-scan
//   P2: stream kq, seeded products; write yb = bf16(x_f32 * m) -> LDS prod-scan
//   P3: stream kq, recompute products, scale by prefix, write kv bf16 in-place
// Block: 32 channels x 32 segments (1024 thr); grid 8*32 = 256 blocks.
// ---------------------------------------------------------------------------
#define SSEG 32
#define SCHB 32
#define SSL (T_SEQ / SSEG)   // 64

__global__ __launch_bounds__(1024, 1)
void scan_kernel(u16* __restrict__ kq, const float* __restrict__ x,
                 u16* __restrict__ yb)
{
    __shared__ float  lmax[SSEG][SCHB];
    __shared__ float2 lprod[SSEG][SCHB];
    const int blk = blockIdx.x;
    const int b   = blk >> 5;                    // / 32 channel-groups
    const int c0  = (blk & 31) * SCHB;
    const int ch  = threadIdx.x & (SCHB - 1);    // 0..31
    const int seg = threadIdx.x >> 5;            // 0..31
    const int c   = c0 + ch;
    const int t0  = seg * SSL;
    const size_t baseh = (size_t)b * T_SEQ * 2048 + 2 * c + (size_t)t0 * 2048;
    const size_t base1 = (size_t)b * T_SEQ * C_DIM + c + (size_t)t0 * C_DIM;

    // P1: streaming segment max (squared magnitudes; sqrt once)
    float m2 = 0.f;
    {
        size_t idx = baseh;
        for (int t = 0; t < SSL; ++t) {
            const u32 v = *(const u32*)&kq[idx];
            const float re = h2f((u16)(v & 0xffffu));
            const float im = h2f((u16)(v >> 16));
            m2 = fmaxf(m2, re * re + im * im);
            idx += 2048;
        }
    }
    lmax[seg][ch] = sqrtf(m2);
    __syncthreads();
    #pragma unroll
    for (int s = 1; s < SSEG; s <<= 1) {
        const float v = lmax[seg][ch];
        const float u = (seg >= s) ? lmax[seg - s][ch] : 0.f;
        __syncthreads();
        lmax[seg][ch] = fmaxf(v, u);
        __syncthreads();
    }
    const float premax = (seg > 0) ? lmax[seg - 1][ch] : 0.f;

    // P2: streaming seeded products; emit yb = bf16(x * m)
    float pr = 1.f, pi = 0.f;
    float m = premax;
    {
        size_t idx = baseh, idx1 = base1;
        for (int t = 0; t < SSL; ++t) {
            const u32 v = *(const u32*)&kq[idx];
            const float re = h2f((u16)(v & 0xffffu));
            const float im = h2f((u16)(v >> 16));
            m = fmaxf(m, sqrtf(re * re + im * im));
            const float inv = 1.f / m;
            const float r0 = re * inv, r1 = im * inv;
            const float nr = pr * r0 - pi * r1;
            const float ni = pr * r1 + pi * r0;
            pr = nr; pi = ni;
            yb[idx1] = f2bf(x[idx1] * m);
            idx += 2048; idx1 += C_DIM;
        }
    }
    lprod[seg][ch] = make_float2(pr, pi);
    __syncthreads();
    #pragma unroll
    for (int s = 1; s < SSEG; s <<= 1) {
        const float2 v = lprod[seg][ch];
        const float2 u = (seg >= s) ? lprod[seg - s][ch] : make_float2(1.f, 0.f);
        __syncthreads();
        lprod[seg][ch] = make_float2(u.x * v.x - u.y * v.y,
                                     u.x * v.y + u.y * v.x);
        __syncthreads();
    }
    float ppr = 1.f, ppi = 0.f;
    if (seg > 0) { const float2 pp = lprod[seg - 1][ch]; ppr = pp.x; ppi = pp.y; }

    // P3: stream again, recompute, scale by prefix, write kv bf16 in-place
    pr = 1.f; pi = 0.f;
    m = premax;
    {
        size_t idx = baseh;
        for (int t = 0; t < SSL; ++t) {
            const u32 v = *(const u32*)&kq[idx];
            const float re = h2f((u16)(v & 0xffffu));
            const float im = h2f((u16)(v >> 16));
            m = fmaxf(m, sqrtf(re * re + im * im));
            const float inv = 1.f / m;
            const float r0 = re * inv, r1 = im * inv;
            const float nr = pr * r0 - pi * r1;
            const float ni = pr * r1 + pi * r0;
            pr = nr; pi = ni;
            const float fr = ppr * nr - ppi * ni;
            const float fi = ppr * ni + ppi * nr;
            *(u32*)&kq[idx] = ((u32)f2bf(fi) << 16) | (u32)f2bf(fr);
            idx += 2048;
        }
    }
}

// ---------------------------------------------------------------------------
// Prep kernels
// ---------------------------------------------------------------------------
__global__ void cvt_bf16(const float* __restrict__ src, u16* __restrict__ dst, int n)
{
    const int i = (blockIdx.x * blockDim.x + threadIdx.x) * 4;
    if (i >= n) return;
    const float4 v = *(const float4*)&src[i];
    ushort4 o;
    o.x = f2bf(v.x); o.y = f2bf(v.y); o.z = f2bf(v.z); o.w = f2bf(v.w);
    *(ushort4*)&dst[i] = o;
}

__global__ void cvt_f16(const float* __restrict__ src, u16* __restrict__ dst, int n)
{
    const int i = (blockIdx.x * blockDim.x + threadIdx.x) * 4;
    if (i >= n) return;
    const float4 v = *(const float4*)&src[i];
    ushort4 o;
    o.x = f2h(v.x); o.y = f2h(v.y); o.z = f2h(v.z); o.w = f2h(v.w);
    *(ushort4*)&dst[i] = o;
}

// Wf/Wg [2,K,N] (tap,k,n) -> Wfgt [tap][F/G][n][k] bf16
__global__ __launch_bounds__(256)
void wtrans(const float* __restrict__ Wf, const float* __restrict__ Wg,
            u16* __restrict__ dst)
{
    __shared__ float tile[64][65];
    const int z = blockIdx.z;
    const float* src = ((z < 2) ? Wf : Wg) + (size_t)(z & 1) * C_DIM * C_DIM;
    u16* d = dst + (size_t)(z & 1) * (2 * C_DIM) * C_DIM
                 + ((z < 2) ? (size_t)0 : (size_t)C_DIM * C_DIM);
    const int k0 = blockIdx.x * 64;
    const int n0 = blockIdx.y * 64;
    const int tx = threadIdx.x & 63, ty = threadIdx.x >> 6;
    #pragma unroll
    for (int i = 0; i < 16; ++i) {
        const int r = ty + i * 4;
        tile[r][tx] = src[(size_t)(k0 + r) * C_DIM + n0 + tx];
    }
    __syncthreads();
    #pragma unroll
    for (int i = 0; i < 16; ++i) {
        const int r = ty + i * 4;
        d[(size_t)(n0 + r) * C_DIM + k0 + tx] = f2bf(tile[tx][r]);
    }
}

// ---------------------------------------------------------------------------
// ws layout (bytes):
//   0         : kq  u16 [16384,2048]  67.1MB  (kh fp16 -> kv bf16 in-place)
//   67108864  : yb  u16 [16384,1024]  33.6MB  (xh fp16 for GEMM1 -> yb bf16)
//   100663296 : hb  u16 [16384,1024]  33.6MB
//   134217728 : Wkh(f16) 4.2 | Wab 4.2 | Wfgt 8.4 | Wob 2.1   (~153MB total)
// ---------------------------------------------------------------------------
extern "C" void kernel_launch(void* const* d_in, const int* in_sizes, int n_in,
                              void* d_out, int out_size, void* d_ws, size_t ws_size,
                              hipStream_t stream)
{
    const float* x  = (const float*)d_in[0];
    const float* Wk = (const float*)d_in[1];
    const float* Wa = (const float*)d_in[2];
    const float* Wf = (const float*)d_in[3];
    const float* Wg = (const float*)d_in[4];
    const float* Wo = (const float*)d_in[5];
    float* out = (float*)d_out;

    const int M = 8 * T_SEQ;
    u16* kq   = (u16*)d_ws;
    u16* yb   = (u16*)((char*)d_ws + 67108864ull);   // xh first, then yb
    u16* hb   = (u16*)((char*)d_ws + 100663296ull);
    u16* Wkh  = (u16*)((char*)d_ws + 134217728ull);
    u16* Wab  = Wkh + 2048 * 1024;
    u16* Wfgt = Wab + 2048 * 1024;
    u16* Wob  = Wfgt + 2ull * 2048 * 1024;

    cvt_f16 <<<(2048 * 1024 / 4 + 255) / 256, 256, 0, stream>>>(Wk, Wkh, 2048 * 1024);
    cvt_bf16<<<(2048 * 1024 / 4 + 255) / 256, 256, 0, stream>>>(Wa, Wab, 2048 * 1024);
    cvt_bf16<<<(1024 * 1024 / 4 + 255) / 256, 256, 0, stream>>>(Wo, Wob, 1024 * 1024);
    wtrans  <<<dim3(16, 16, 4), 256, 0, stream>>>(Wf, Wg, Wfgt);
    cvt_f16 <<<(M * 1024 / 4) / 256, 256, 0, stream>>>(x, yb, M * 1024);  // xh

    // 1) kq = fp16( x @ Wk^T )  (fp16 MFMA, fp16 output)
    mfma_gemm<0, 2, 1><<<dim3(2048 / BN, M / BM), 256, 0, stream>>>(
        yb, Wkh, kq, M, 2048, 1024);

    // 2) streaming scan: kv bf16 in-place over kq; yb = bf16(x*scale)
    scan_kernel<<<256, 1024, 0, stream>>>(kq, x, yb);

    // 3) out = kv @ Wa^T  (bf16 A via global_load_lds)
    mfma_gemm<0, 0, 0><<<dim3(1024 / BN, M / BM), 256, 0, stream>>>(
        kq, Wab, out, M, 1024, 2048);

    // 4) hb = bf16(tanh(conv(yb,Wf)) * sigmoid(conv(yb,Wg)))
    conv_gate<<<dim3(1024 / BN, M / BM), 256, 0, stream>>>(yb, Wfgt, hb, M);

    // 5) out *= hb @ Wo^T
    mfma_gemm<0, 1, 0><<<dim3(1024 / BN, M / BM), 256, 0, stream>>>(
        hb, Wob, out, M, 1024, 1024);
}

// Round 10
// 472.988 us; speedup vs baseline: 1.5283x; 1.0699x over previous
//
#include <hip/hip_runtime.h>
#include <cmath>

#define T_SEQ 2048
#define C_DIM 1024
#define BM 128
#define BN 128
#define BK 32

typedef unsigned short u16;
typedef unsigned int u32;
typedef short bf16x8 __attribute__((ext_vector_type(8)));
typedef _Float16 f16x8 __attribute__((ext_vector_type(8)));
typedef float f32x4 __attribute__((ext_vector_type(4)));
typedef unsigned short u16x8 __attribute__((ext_vector_type(8)));

#define AS1 __attribute__((address_space(1)))
#define AS3 __attribute__((address_space(3)))

__device__ __forceinline__ u16 f2bf(float f) {
    u32 u = __builtin_bit_cast(u32, f);
    u32 r = u + 0x7fffu + ((u >> 16) & 1u);
    return (u16)(r >> 16);
}
__device__ __forceinline__ u16 f2h(float f) {
    return __builtin_bit_cast(u16, (_Float16)f);
}
__device__ __forceinline__ float h2f(u16 h) {
    return (float)__builtin_bit_cast(_Float16, h);
}
__device__ __forceinline__ float bf2f(u16 h) {
    return __builtin_bit_cast(float, (u32)h << 16);
}
__device__ __forceinline__ void gl_lds16(const void* g, void* l) {
    __builtin_amdgcn_global_load_lds((const AS1 u32*)g, (AS3 u32*)l, 16, 0, 0);
}

// XCD-aware bijective block swizzle (T1): all our grids have nwg % 8 == 0.
__device__ __forceinline__ int xcd_swz(int lin, int nwg) {
    return (lin & 7) * (nwg >> 3) + (lin >> 3);
}

// ---------------------------------------------------------------------------
// MFMA GEMM (used for GEMM1): C = A @ B^T, A 16-bit via global_load_lds.
// EPI: 0 = C f32 = acc   2 = C u16 = fp16(acc)
// DT:  0 = bf16  1 = fp16
// ---------------------------------------------------------------------------
template<int EPI, int DT>
__global__ __launch_bounds__(256)
void mfma_gemm(const u16* __restrict__ Ap, const u16* __restrict__ B0,
               void* __restrict__ Cout, int M, int N, int K)
{
    __shared__ u16 lds[2 * 2 * 4096];   // 2 buffers x (A, B) x 8KB
    const int tid  = threadIdx.x;
    const int lane = tid & 63;
    const int wid  = tid >> 6;
    const int wr = wid >> 1, wc = wid & 1;
    const int gx = gridDim.x;
    const int lin = xcd_swz(blockIdx.x + gx * blockIdx.y, gx * gridDim.y);
    const int m0 = (lin / gx) * BM;
    const int n0 = (lin % gx) * BN;
    const int NT = K / BK;

    f32x4 acc[4][4] = {};

    auto stage = [&](int it, int buf) {
        const int k0 = it * BK;
        u16* base = &lds[buf * 8192];
        #pragma unroll
        for (int i = 0; i < 2; ++i) {
            const int chunk = wid + 4 * i;
            const int rloc  = chunk * 16 + (lane >> 2);
            const int slot  = (lane & 3) ^ ((rloc >> 1) & 3);
            gl_lds16(B0 + (size_t)(n0 + rloc) * K + k0 + slot * 8,
                     base + 4096 + chunk * 512);
            gl_lds16(Ap + (size_t)(m0 + rloc) * K + k0 + slot * 8,
                     base + chunk * 512);
        }
    };

    auto compute = [&](int buf) {
        const u16* base = &lds[buf * 8192];
        if constexpr (DT == 0) {
            bf16x8 a[4], b[4];
            #pragma unroll
            for (int f = 0; f < 4; ++f) {
                const int row = wr * 64 + f * 16 + (lane & 15);
                const int sp  = ((lane >> 4) & 3) ^ ((row >> 1) & 3);
                a[f] = *(const bf16x8*)&base[row * 32 + sp * 8];
                const int rowb = wc * 64 + f * 16 + (lane & 15);
                const int spb  = ((lane >> 4) & 3) ^ ((rowb >> 1) & 3);
                b[f] = *(const bf16x8*)&base[4096 + rowb * 32 + spb * 8];
            }
            #pragma unroll
            for (int fm = 0; fm < 4; ++fm)
                #pragma unroll
                for (int fn = 0; fn < 4; ++fn)
                    acc[fm][fn] = __builtin_amdgcn_mfma_f32_16x16x32_bf16(a[fm], b[fn], acc[fm][fn], 0, 0, 0);
        } else {
            f16x8 a[4], b[4];
            #pragma unroll
            for (int f = 0; f < 4; ++f) {
                const int row = wr * 64 + f * 16 + (lane & 15);
                const int sp  = ((lane >> 4) & 3) ^ ((row >> 1) & 3);
                a[f] = *(const f16x8*)&base[row * 32 + sp * 8];
                const int rowb = wc * 64 + f * 16 + (lane & 15);
                const int spb  = ((lane >> 4) & 3) ^ ((rowb >> 1) & 3);
                b[f] = *(const f16x8*)&base[4096 + rowb * 32 + spb * 8];
            }
            #pragma unroll
            for (int fm = 0; fm < 4; ++fm)
                #pragma unroll
                for (int fn = 0; fn < 4; ++fn)
                    acc[fm][fn] = __builtin_amdgcn_mfma_f32_16x16x32_f16(a[fm], b[fn], acc[fm][fn], 0, 0, 0);
        }
    };

    stage(0, 0);
    int cur = 0;
    for (int it = 0; it < NT; ++it) {
        __syncthreads();
        if (it + 1 < NT) stage(it + 1, cur ^ 1);
        compute(cur);
        cur ^= 1;
    }

    const int crow0 = m0 + wr * 64 + ((lane >> 4) << 2);
    const int ccol  = n0 + wc * 64 + (lane & 15);
    #pragma unroll
    for (int fm = 0; fm < 4; ++fm)
        #pragma unroll
        for (int fn = 0; fn < 4; ++fn)
            #pragma unroll
            for (int r = 0; r < 4; ++r) {
                const size_t idx = (size_t)(crow0 + fm * 16 + r) * N + ccol + fn * 16;
                if constexpr (EPI == 0) ((float*)Cout)[idx] = acc[fm][fn][r];
                else                    ((u16*)Cout)[idx] = f2h(acc[fm][fn][r]);
            }
}

// ---------------------------------------------------------------------------
// Dual GEMM + product epilogue:
//   out = (A1 @ B1^T) * (A2 @ B2^T)   elementwise, f32 out
// A1 = kv bf16 [M,K1=2048], B1 = Wab [N,K1]; A2 = hb [M,K2=1024], B2 = Wob.
// Two sequenced pipelined K-loops sharing the LDS dbuf; phase boundary
// prefetches phase-2's first tile (no bubble).
// ---------------------------------------------------------------------------
__global__ __launch_bounds__(256)
void dual_gemm(const u16* __restrict__ A1, const u16* __restrict__ B1, int K1,
               const u16* __restrict__ A2, const u16* __restrict__ B2, int K2,
               float* __restrict__ out, int M, int N)
{
    __shared__ u16 lds[2 * 2 * 4096];
    const int tid  = threadIdx.x;
    const int lane = tid & 63;
    const int wid  = tid >> 6;
    const int wr = wid >> 1, wc = wid & 1;
    const int gx = gridDim.x;
    const int lin = xcd_swz(blockIdx.x + gx * blockIdx.y, gx * gridDim.y);
    const int m0 = (lin / gx) * BM;
    const int n0 = (lin % gx) * BN;

    f32x4 acc1[4][4] = {};
    f32x4 acc2[4][4] = {};

    auto stage = [&](const u16* Ap, const u16* Bp, int K, int it, int buf) {
        const int k0 = it * BK;
        u16* base = &lds[buf * 8192];
        #pragma unroll
        for (int i = 0; i < 2; ++i) {
            const int chunk = wid + 4 * i;
            const int rloc  = chunk * 16 + (lane >> 2);
            const int slot  = (lane & 3) ^ ((rloc >> 1) & 3);
            gl_lds16(Bp + (size_t)(n0 + rloc) * K + k0 + slot * 8,
                     base + 4096 + chunk * 512);
            gl_lds16(Ap + (size_t)(m0 + rloc) * K + k0 + slot * 8,
                     base + chunk * 512);
        }
    };

    auto compute = [&](int buf, f32x4 (&acc)[4][4]) {
        const u16* base = &lds[buf * 8192];
        bf16x8 a[4], b[4];
        #pragma unroll
        for (int f = 0; f < 4; ++f) {
            const int row = wr * 64 + f * 16 + (lane & 15);
            const int sp  = ((lane >> 4) & 3) ^ ((row >> 1) & 3);
            a[f] = *(const bf16x8*)&base[row * 32 + sp * 8];
            const int rowb = wc * 64 + f * 16 + (lane & 15);
            const int spb  = ((lane >> 4) & 3) ^ ((rowb >> 1) & 3);
            b[f] = *(const bf16x8*)&base[4096 + rowb * 32 + spb * 8];
        }
        #pragma unroll
        for (int fm = 0; fm < 4; ++fm)
            #pragma unroll
            for (int fn = 0; fn < 4; ++fn)
                acc[fm][fn] = __builtin_amdgcn_mfma_f32_16x16x32_bf16(a[fm], b[fn], acc[fm][fn], 0, 0, 0);
    };

    const int NT1 = K1 / BK, NT2 = K2 / BK;
    stage(A1, B1, K1, 0, 0);
    int cur = 0;
    for (int it = 0; it < NT1; ++it) {
        __syncthreads();
        if (it + 1 < NT1) stage(A1, B1, K1, it + 1, cur ^ 1);
        else              stage(A2, B2, K2, 0, cur ^ 1);   // cross-phase prefetch
        compute(cur, acc1);
        cur ^= 1;
    }
    for (int it = 0; it < NT2; ++it) {
        __syncthreads();
        if (it + 1 < NT2) stage(A2, B2, K2, it + 1, cur ^ 1);
        compute(cur, acc2);
        cur ^= 1;
    }

    const int crow0 = m0 + wr * 64 + ((lane >> 4) << 2);
    const int ccol  = n0 + wc * 64 + (lane & 15);
    #pragma unroll
    for (int fm = 0; fm < 4; ++fm)
        #pragma unroll
        for (int fn = 0; fn < 4; ++fn)
            #pragma unroll
            for (int r = 0; r < 4; ++r) {
                const size_t idx = (size_t)(crow0 + fm * 16 + r) * N + ccol + fn * 16;
                out[idx] = acc1[fm][fn][r] * acc2[fm][fn][r];
            }
}

// ---------------------------------------------------------------------------
// Fused causal-conv + gate:  H = bf16( tanh(conv(y,Wf)) * sigmoid(conv(y,Wg)) )
// ---------------------------------------------------------------------------
__global__ __launch_bounds__(256)
void conv_gate(const u16* __restrict__ A, const u16* __restrict__ Wfgt,
               u16* __restrict__ H, int M)
{
    constexpr int KIT = C_DIM / BK;   // 32
    constexpr int NT  = 2 * KIT;      // 64
    __shared__ u16 lds[2 * 3 * 4096]; // 2 buf x (A, BF, BG)
    const int tid  = threadIdx.x;
    const int lane = tid & 63;
    const int wid  = tid >> 6;
    const int wr = wid >> 1, wc = wid & 1;
    const int gx = gridDim.x;
    const int lin = xcd_swz(blockIdx.x + gx * blockIdx.y, gx * gridDim.y);
    const int m0 = (lin / gx) * BM;
    const int n0 = (lin % gx) * BN;

    f32x4 accF[4][4] = {};
    f32x4 accG[4][4] = {};

    auto stage = [&](int it, int buf) {
        const int p  = it / KIT;                 // tap
        const int k0 = (it - p * KIT) * BK;
        u16* base = &lds[buf * 12288];
        const u16* BF = Wfgt + (size_t)p * 2 * C_DIM * C_DIM;
        const u16* BG = BF + (size_t)C_DIM * C_DIM;
        const int sh = (p == 0) ? 1 : 0;
        #pragma unroll
        for (int i = 0; i < 2; ++i) {
            const int chunk = wid + 4 * i;
            const int rloc  = chunk * 16 + (lane >> 2);
            const int slot  = (lane & 3) ^ ((rloc >> 1) & 3);
            int grow = m0 + rloc - sh;
            if (grow < 0) grow = 0;
            gl_lds16(A + (size_t)grow * C_DIM + k0 + slot * 8,
                     base + chunk * 512);
            gl_lds16(BF + (size_t)(n0 + rloc) * C_DIM + k0 + slot * 8,
                     base + 4096 + chunk * 512);
            gl_lds16(BG + (size_t)(n0 + rloc) * C_DIM + k0 + slot * 8,
                     base + 8192 + chunk * 512);
        }
    };

    auto compute = [&](int buf) {
        const u16* base = &lds[buf * 12288];
        bf16x8 a[4], bf[4], bg[4];
        #pragma unroll
        for (int f = 0; f < 4; ++f) {
            const int row = wr * 64 + f * 16 + (lane & 15);
            const int sp  = ((lane >> 4) & 3) ^ ((row >> 1) & 3);
            a[f] = *(const bf16x8*)&base[row * 32 + sp * 8];
            const int rowb = wc * 64 + f * 16 + (lane & 15);
            const int spb  = ((lane >> 4) & 3) ^ ((rowb >> 1) & 3);
            bf[f] = *(const bf16x8*)&base[4096 + rowb * 32 + spb * 8];
            bg[f] = *(const bf16x8*)&base[8192 + rowb * 32 + spb * 8];
        }
        #pragma unroll
        for (int fm = 0; fm < 4; ++fm)
            #pragma unroll
            for (int fn = 0; fn < 4; ++fn) {
                accF[fm][fn] = __builtin_amdgcn_mfma_f32_16x16x32_bf16(a[fm], bf[fn], accF[fm][fn], 0, 0, 0);
                accG[fm][fn] = __builtin_amdgcn_mfma_f32_16x16x32_bf16(a[fm], bg[fn], accG[fm][fn], 0, 0, 0);
            }
    };

    stage(0, 0);
    int cur = 0;
    for (int it = 0; it < NT; ++it) {
        __syncthreads();
        // zero the t==0 row of the A tile for the shifted tap
        if ((it / KIT) == 0 && (m0 % T_SEQ) == 0) {
            if (tid < 4) {
                u16x8 z = {0,0,0,0,0,0,0,0};
                *(u16x8*)&lds[cur * 12288 + tid * 8] = z;
            }
            __syncthreads();
        }
        if (it + 1 < NT) stage(it + 1, cur ^ 1);
        compute(cur);
        cur ^= 1;
    }

    const int crow0 = m0 + wr * 64 + ((lane >> 4) << 2);
    const int ccol  = n0 + wc * 64 + (lane & 15);
    #pragma unroll
    for (int fm = 0; fm < 4; ++fm)
        #pragma unroll
        for (int fn = 0; fn < 4; ++fn)
            #pragma unroll
            for (int r = 0; r < 4; ++r) {
                const float fv = accF[fm][fn][r];
                const float gv = accG[fm][fn][r];
                const float th = 1.0f - 2.0f / (expf(2.0f * fv) + 1.0f);
                const float sg = 1.0f / (1.0f + expf(-gv));
                H[(size_t)(crow0 + fm * 16 + r) * C_DIM + ccol + fn * 16] = f2bf(th * sg);
            }
}

// ---------------------------------------------------------------------------
// Segmented parallel scan, 3-pass streaming, 128B-coalesced:
//   P1: stream kq, segment max -> LDS max-scan
//   P2: stream kq, seeded products; yb = bf16(h2f(xh) * m) in-place -> prod-scan
//   P3: stream kq, recompute, scale by prefix, write kv bf16 in-place
// Block: 32 channels x 32 segments (1024 thr); grid 8*32 = 256 blocks.
// ---------------------------------------------------------------------------
#define SSEG 32
#define SCHB 32
#define SSL (T_SEQ / SSEG)   // 64

__global__ __launch_bounds__(1024, 1)
void scan_kernel(u16* __restrict__ kq, u16* __restrict__ xyb)
{
    __shared__ float  lmax[SSEG][SCHB];
    __shared__ float2 lprod[SSEG][SCHB];
    const int blk = blockIdx.x;
    const int b   = blk >> 5;
    const int c0  = (blk & 31) * SCHB;
    const int ch  = threadIdx.x & (SCHB - 1);
    const int seg = threadIdx.x >> 5;
    const int c   = c0 + ch;
    const int t0  = seg * SSL;
    const size_t baseh = (size_t)b * T_SEQ * 2048 + 2 * c + (size_t)t0 * 2048;
    const size_t base1 = (size_t)b * T_SEQ * C_DIM + c + (size_t)t0 * C_DIM;

    // P1: streaming segment max (squared magnitudes; sqrt once)
    float m2 = 0.f;
    {
        size_t idx = baseh;
        for (int t = 0; t < SSL; ++t) {
            const u32 v = *(const u32*)&kq[idx];
            const float re = h2f((u16)(v & 0xffffu));
            const float im = h2f((u16)(v >> 16));
            m2 = fmaxf(m2, re * re + im * im);
            idx += 2048;
        }
    }
    lmax[seg][ch] = sqrtf(m2);
    __syncthreads();
    #pragma unroll
    for (int s = 1; s < SSEG; s <<= 1) {
        const float v = lmax[seg][ch];
        const float u = (seg >= s) ? lmax[seg - s][ch] : 0.f;
        __syncthreads();
        lmax[seg][ch] = fmaxf(v, u);
        __syncthreads();
    }
    const float premax = (seg > 0) ? lmax[seg - 1][ch] : 0.f;

    // P2: streaming seeded products; yb = bf16(xh * m) in-place
    float pr = 1.f, pi = 0.f;
    float m = premax;
    {
        size_t idx = baseh, idx1 = base1;
        for (int t = 0; t < SSL; ++t) {
            const u32 v = *(const u32*)&kq[idx];
            const float re = h2f((u16)(v & 0xffffu));
            const float im = h2f((u16)(v >> 16));
            m = fmaxf(m, sqrtf(re * re + im * im));
            const float inv = 1.f / m;
            const float r0 = re * inv, r1 = im * inv;
            const float nr = pr * r0 - pi * r1;
            const float ni = pr * r1 + pi * r0;
            pr = nr; pi = ni;
            const float xv = h2f(xyb[idx1]);
            xyb[idx1] = f2bf(xv * m);
            idx += 2048; idx1 += C_DIM;
        }
    }
    lprod[seg][ch] = make_float2(pr, pi);
    __syncthreads();
    #pragma unroll
    for (int s = 1; s < SSEG; s <<= 1) {
        const float2 v = lprod[seg][ch];
        const float2 u = (seg >= s) ? lprod[seg - s][ch] : make_float2(1.f, 0.f);
        __syncthreads();
        lprod[seg][ch] = make_float2(u.x * v.x - u.y * v.y,
                                     u.x * v.y + u.y * v.x);
        __syncthreads();
    }
    float ppr = 1.f, ppi = 0.f;
    if (seg > 0) { const float2 pp = lprod[seg - 1][ch]; ppr = pp.x; ppi = pp.y; }

    // P3: stream again, recompute, scale by prefix, write kv bf16 in-place
    pr = 1.f; pi = 0.f;
    m = premax;
    {
        size_t idx = baseh;
        for (int t = 0; t < SSL; ++t) {
            const u32 v = *(const u32*)&kq[idx];
            const float re = h2f((u16)(v & 0xffffu));
            const float im = h2f((u16)(v >> 16));
            m = fmaxf(m, sqrtf(re * re + im * im));
            const float inv = 1.f / m;
            const float r0 = re * inv, r1 = im * inv;
            const float nr = pr * r0 - pi * r1;
            const float ni = pr * r1 + pi * r0;
            pr = nr; pi = ni;
            const float fr = ppr * nr - ppi * ni;
            const float fi = ppr * ni + ppi * nr;
            *(u32*)&kq[idx] = ((u32)f2bf(fi) << 16) | (u32)f2bf(fr);
            idx += 2048;
        }
    }
}

// ---------------------------------------------------------------------------
// Prep kernels
// ---------------------------------------------------------------------------
__global__ void cvt_bf16(const float* __restrict__ src, u16* __restrict__ dst, int n)
{
    const int i = (blockIdx.x * blockDim.x + threadIdx.x) * 4;
    if (i >= n) return;
    const float4 v = *(const float4*)&src[i];
    ushort4 o;
    o.x = f2bf(v.x); o.y = f2bf(v.y); o.z = f2bf(v.z); o.w = f2bf(v.w);
    *(ushort4*)&dst[i] = o;
}

__global__ void cvt_f16(const float* __restrict__ src, u16* __restrict__ dst, int n)
{
    const int i = (blockIdx.x * blockDim.x + threadIdx.x) * 4;
    if (i >= n) return;
    const float4 v = *(const float4*)&src[i];
    ushort4 o;
    o.x = f2h(v.x); o.y = f2h(v.y); o.z = f2h(v.z); o.w = f2h(v.w);
    *(ushort4*)&dst[i] = o;
}

// Wf/Wg [2,K,N] (tap,k,n) -> Wfgt [tap][F/G][n][k] bf16
__global__ __launch_bounds__(256)
void wtrans(const float* __restrict__ Wf, const float* __restrict__ Wg,
            u16* __restrict__ dst)
{
    __shared__ float tile[64][65];
    const int z = blockIdx.z;
    const float* src = ((z < 2) ? Wf : Wg) + (size_t)(z & 1) * C_DIM * C_DIM;
    u16* d = dst + (size_t)(z & 1) * (2 * C_DIM) * C_DIM
                 + ((z < 2) ? (size_t)0 : (size_t)C_DIM * C_DIM);
    const int k0 = blockIdx.x * 64;
    const int n0 = blockIdx.y * 64;
    const int tx = threadIdx.x & 63, ty = threadIdx.x >> 6;
    #pragma unroll
    for (int i = 0; i < 16; ++i) {
        const int r = ty + i * 4;
        tile[r][tx] = src[(size_t)(k0 + r) * C_DIM + n0 + tx];
    }
    __syncthreads();
    #pragma unroll
    for (int i = 0; i < 16; ++i) {
        const int r = ty + i * 4;
        d[(size_t)(n0 + r) * C_DIM + k0 + tx] = f2bf(tile[tx][r]);
    }
}

// ---------------------------------------------------------------------------
// ws layout (bytes):
//   0         : kq  u16 [16384,2048]  67.1MB  (kh fp16 -> kv bf16 in-place)
//   67108864  : yb  u16 [16384,1024]  33.6MB  (xh fp16 -> yb bf16 in-place)
//   100663296 : hb  u16 [16384,1024]  33.6MB
//   134217728 : Wkh(f16) 4.2 | Wab 4.2 | Wfgt 8.4 | Wob 2.1   (~153MB total)
// ---------------------------------------------------------------------------
extern "C" void kernel_launch(void* const* d_in, const int* in_sizes, int n_in,
                              void* d_out, int out_size, void* d_ws, size_t ws_size,
                              hipStream_t stream)
{
    const float* x  = (const float*)d_in[0];
    const float* Wk = (const float*)d_in[1];
    const float* Wa = (const float*)d_in[2];
    const float* Wf = (const float*)d_in[3];
    const float* Wg = (const float*)d_in[4];
    const float* Wo = (const float*)d_in[5];
    float* out = (float*)d_out;

    const int M = 8 * T_SEQ;
    u16* kq   = (u16*)d_ws;
    u16* yb   = (u16*)((char*)d_ws + 67108864ull);   // xh first, then yb
    u16* hb   = (u16*)((char*)d_ws + 100663296ull);
    u16* Wkh  = (u16*)((char*)d_ws + 134217728ull);
    u16* Wab  = Wkh + 2048 * 1024;
    u16* Wfgt = Wab + 2048 * 1024;
    u16* Wob  = Wfgt + 2ull * 2048 * 1024;

    cvt_f16 <<<(2048 * 1024 / 4 + 255) / 256, 256, 0, stream>>>(Wk, Wkh, 2048 * 1024);
    cvt_bf16<<<(2048 * 1024 / 4 + 255) / 256, 256, 0, stream>>>(Wa, Wab, 2048 * 1024);
    cvt_bf16<<<(1024 * 1024 / 4 + 255) / 256, 256, 0, stream>>>(Wo, Wob, 1024 * 1024);
    wtrans  <<<dim3(16, 16, 4), 256, 0, stream>>>(Wf, Wg, Wfgt);
    cvt_f16 <<<(M * 1024 / 4) / 256, 256, 0, stream>>>(x, yb, M * 1024);  // xh

    // 1) kq = fp16( x @ Wk^T )  (fp16 MFMA, fp16 output)
    mfma_gemm<2, 1><<<dim3(2048 / BN, M / BM), 256, 0, stream>>>(
        yb, Wkh, kq, M, 2048, 1024);

    // 2) streaming scan: kv bf16 in-place over kq; yb = bf16(xh*scale) in-place
    scan_kernel<<<256, 1024, 0, stream>>>(kq, yb);

    // 3) hb = bf16(tanh(conv(yb,Wf)) * sigmoid(conv(yb,Wg)))
    conv_gate<<<dim3(1024 / BN, M / BM), 256, 0, stream>>>(yb, Wfgt, hb, M);

    // 4) out = (kv @ Wa^T) * (hb @ Wo^T)   (dual GEMM, product epilogue)
    dual_gemm<<<dim3(1024 / BN, M / BM), 256, 0, stream>>>(
        kq, Wab, 2048, hb, Wob, 1024, out, M, 1024);
}